// Round 15
// baseline (84.612 us; speedup 1.0000x reference)
//
#include <hip/hip_runtime.h>

#define NSTEP  730
#define NGRID  2000
#define PRECSf 1e-5f

#define GLOBAL_AS __attribute__((address_space(1)))
#define LDS_AS    __attribute__((address_space(3)))

__device__ __forceinline__ float fast_exp2(float v) { return __builtin_amdgcn_exp2f(v); }
__device__ __forceinline__ float fast_log2(float v) { return __builtin_amdgcn_logf(v); }
__device__ __forceinline__ float med3(float a, float b, float c) {
    return __builtin_amdgcn_fmed3f(a, b, c);
}

struct Par {
    float TT, cfmax, cfmaxTT, cfrXcf, cfrTT, CWH;
    float beta, betaC, FC, betaet, betaetC;
    float PERC, omK0, k0uzl, omK1, K2;
};

#define MEMFENCE() asm volatile("" ::: "memory")
#define WAITV(N)  asm volatile("s_waitcnt vmcnt(" #N ")" ::: "memory")

// routing sub-step: needs only inflow; advances SUZ/SLZ; returns q
__device__ __forceinline__ float route_step(float infl,
        float& SUZ, float& SLZ, const Par& c)
{
    const float SUZ1  = SUZ + infl;
    const float PERCv = fminf(SUZ1, c.PERC);
    const float SUZ2  = SUZ1 - PERCv;
    const float SUZ3  = fminf(SUZ2, fmaf(c.omK0, SUZ2, c.k0uzl));
    const float SUZ4  = c.omK1 * SUZ3;
    SUZ = SUZ4;
    const float SLZ1 = SLZ + PERCv;
    const float Q2   = c.K2 * SLZ1;
    SLZ = SLZ1 - Q2;
    return (SUZ2 - SUZ4) + Q2;
}

// fused step I: SM chain (4 HW trans; Et folded into evap exponent so the
// chain tail is exp2->sub->max3) + routing I-1 + snow of chunk k+1, fills
// source-placed inside the trans-latency gaps.
template<int I, bool SNOW>
__device__ __forceinline__ void step1(const float4 (&xv)[16],
        const float (&A)[16], const float (&Ets)[16], const float (&cEts)[16],
        float (&An)[16], float (&Etn)[16], float (&cEtn)[16],
        float (&qbuf)[16], float& infl,
        float& SM, float& SUZ, float& SLZ,
        float& SP, float& MW, const Par& c)
{
    const float Ac   = A[I];
    const float Et   = Ets[I];
    const float cEt  = cEts[I];
    const float SMpA = SM + Ac;
    const float lg   = fast_log2(SM);                        // T1
    // --- fill 1: snow front half ---
    float rain = 0.0f, SP2v = 0.0f, MW1v = 0.0f, rrawv = 0.0f, Ex = 0.0f;
    if constexpr (SNOW) {
        const float Pt = xv[I].x, Tt = xv[I].y;
        Ex = xv[I].z;
        const float snow = (Tt < c.TT) ? Pt : 0.0f;
        rain = Pt - snow;
        const float mraw = fmaf(c.cfmax, Tt, -c.cfmaxTT);
        rrawv = fmaf(-c.cfrXcf, Tt, c.cfrTT);
        const float SP1 = SP + snow;
        SP2v = med3(SP1 - mraw, 0.0f, SP1);                  // exact: SP1 >= 0
        MW1v = MW + (SP1 - SP2v);
    }
    const float sw = fast_exp2(fmaf(c.beta, lg, c.betaC));   // T2
    // --- fill 2: routing of step I-1 ---
    if constexpr (I >= 1) qbuf[I - 1] = route_step(infl, SUZ, SLZ, c);
    const float SM1 = fmaf(-Ac, sw, SMpA);
    const float lg1 = fast_log2(SM1);                        // T3
    // --- fill 3: snow back half ---
    if constexpr (SNOW) {
        const float MW2 = med3(MW1v - rrawv, 0.0f, MW1v);    // exact: MW1 >= 0
        SP = SP2v + (MW1v - MW2);
        const float tosoil = fmaxf(fmaf(-c.CWH, SP, MW2), 0.0f);
        MW = MW2 - tosoil;
        An[I]  = rain + tosoil;
        Etn[I] = Ex;
        cEtn[I] = c.betaetC + fmaxf(fast_log2(Ex), -200.0f); // Et fold (off-chain)
    }
    const float SM2 = fminf(SM1, c.FC);
    infl = SMpA - SM2;                                       // recharge + excess
    const float Ete = fast_exp2(fmaf(c.betaet, lg1, cEt));   // T4: Et*(SM1/LPFC)^bet
    SM = fmaxf(fmaxf(SM2 - Ete, SM2 - Et), PRECSf);          // v_max3
}

template<int I, int NS, bool SNOW>
__device__ __forceinline__ void steps_pass(const float4 (&xv)[16],
        const float (&A)[16], const float (&Ets)[16], const float (&cEts)[16],
        float (&An)[16], float (&Etn)[16], float (&cEtn)[16],
        float (&qbuf)[16], float& infl,
        float& SM, float& SUZ, float& SLZ,
        float& SP, float& MW, const Par& c)
{
    if constexpr (I < NS) {
        step1<I, SNOW>(xv, A, Ets, cEts, An, Etn, cEtn, qbuf, infl,
                       SM, SUZ, SLZ, SP, MW, c);
        steps_pass<I + 1, NS, SNOW>(xv, A, Ets, cEts, An, Etn, cEtn, qbuf, infl,
                                    SM, SUZ, SLZ, SP, MW, c);
    }
}

// prologue-only: snow for chunk 0
template<int I, int NS>
__device__ __forceinline__ void snow_pass(const float4 (&xv)[16],
        float& SP, float& MW, float (&A)[16], float (&Ets)[16], float (&cEts)[16],
        const Par& c)
{
    if constexpr (I < NS) {
        const float Pt = xv[I].x, Tt = xv[I].y, Ex = xv[I].z;
        const float snow = (Tt < c.TT) ? Pt : 0.0f;
        const float rain = Pt - snow;
        const float mraw = fmaf(c.cfmax, Tt, -c.cfmaxTT);
        const float rraw = fmaf(-c.cfrXcf, Tt, c.cfrTT);
        const float SP1  = SP + snow;
        const float SP2  = med3(SP1 - mraw, 0.0f, SP1);
        const float MW1  = MW + (SP1 - SP2);
        const float MW2  = med3(MW1 - rraw, 0.0f, MW1);
        SP = SP2 + (MW1 - MW2);
        const float tosoil = fmaxf(fmaf(-c.CWH, SP, MW2), 0.0f);
        MW = MW2 - tosoil;
        A[I]   = rain + tosoil;
        Ets[I] = Ex;
        cEts[I] = c.betaetC + fmaxf(fast_log2(Ex), -200.0f);
        snow_pass<I + 1, NS>(xv, SP, MW, A, Ets, cEts, c);
    }
}

// hoisted LDS->reg burst for one chunk (fences pin it; scalar pin anchors values)
#define LOAD_XV(B)                                                             \
    _Pragma("unroll")                                                          \
    for (int ii = 0; ii < 16; ++ii)                                            \
        xv[ii] = *reinterpret_cast<const float4*>(&xs[B][ii * 16 + crow * 4]); \
    asm volatile("" :: "v"(xv[0].x),  "v"(xv[1].x),  "v"(xv[2].x),             \
                       "v"(xv[3].x),  "v"(xv[4].x),  "v"(xv[5].x),             \
                       "v"(xv[6].x),  "v"(xv[7].x),  "v"(xv[8].x),             \
                       "v"(xv[9].x),  "v"(xv[10].x), "v"(xv[11].x),            \
                       "v"(xv[12].x), "v"(xv[13].x), "v"(xv[14].x),            \
                       "v"(xv[15].x))

// chunk-end reduce: transpose 16x16 (per cell) through LDS, tree-sum, store.
// stride 20 floats: conflict-free (R11 measured SQ_LDS_BANK_CONFLICT = 0).
#define REDUCE_STORE(T0, N) do {                                               \
    float* qrow = &qt[crow * 336 + m * 20];                                    \
    *reinterpret_cast<float4*>(qrow + 0)  = make_float4(qbuf[0], qbuf[1], qbuf[2], qbuf[3]);    \
    *reinterpret_cast<float4*>(qrow + 4)  = make_float4(qbuf[4], qbuf[5], qbuf[6], qbuf[7]);    \
    *reinterpret_cast<float4*>(qrow + 8)  = make_float4(qbuf[8], qbuf[9], qbuf[10], qbuf[11]);  \
    *reinterpret_cast<float4*>(qrow + 12) = make_float4(qbuf[12], qbuf[13], qbuf[14], qbuf[15]);\
    const float* qcol = &qt[crow * 336 + m];                                   \
    float s0 = qcol[0*20]  + qcol[1*20];                                       \
    float s1 = qcol[2*20]  + qcol[3*20];                                       \
    float s2 = qcol[4*20]  + qcol[5*20];                                       \
    float s3 = qcol[6*20]  + qcol[7*20];                                       \
    float s4 = qcol[8*20]  + qcol[9*20];                                       \
    float s5 = qcol[10*20] + qcol[11*20];                                      \
    float s6 = qcol[12*20] + qcol[13*20];                                      \
    float s7 = qcol[14*20] + qcol[15*20];                                      \
    s0 += s1; s2 += s3; s4 += s5; s6 += s7;                                    \
    s0 += s2; s4 += s6; s0 += s4;                                              \
    if (m < (N)) out[(size_t)((T0) + m) * NGRID + g] = s0 * 0.0625f;           \
} while (0)

__global__ __launch_bounds__(64, 1)
void hbv_kernel(const float* __restrict__ x,
                const float* __restrict__ params,
                float* __restrict__ out)
{
    // one wave per block: 4 grid cells x 16 members. No barriers needed.
    __shared__ __align__(16) float xs[2][256];   // staging [buf][i*16 + c*4 + comp]
    __shared__ __align__(16) float qt[4 * 336];  // q transpose scratch

    const int lane = threadIdx.x;        // 0..63
    const int g0   = blockIdx.x * 4;
    const int crow = lane >> 4;          // cell within block
    const int m    = lane & 15;          // ensemble member
    const int g    = g0 + crow;

    // per-lane staging source: instruction j stages LDS flat index j*64+lane
    const float* srcb[4];
    int ioff[4];
#pragma unroll
    for (int j = 0; j < 4; ++j) {
        const int flat = j * 64 + lane;
        const int i    = flat >> 4;
        const int cc   = (flat >> 2) & 3;
        int comp       = flat & 3; if (comp == 3) comp = 0;   // pad slot
        srcb[j] = x + (size_t)(g0 + cc) * 3 + comp;
        ioff[j] = i;
    }

#define ISSUE(B, T0) do {                                                      \
    MEMFENCE();                                                                \
    _Pragma("unroll")                                                          \
    for (int j = 0; j < 4; ++j) {                                              \
        int stp = (T0) + ioff[j]; stp = stp < NSTEP ? stp : NSTEP - 1;         \
        const float* s_ = srcb[j] + (size_t)stp * (NGRID * 3);                 \
        __builtin_amdgcn_global_load_lds((const GLOBAL_AS unsigned*)s_,        \
            (LDS_AS unsigned*)&xs[B][j * 64], 4, 0, 0);                        \
    }                                                                          \
    MEMFENCE();                                                                \
} while (0)

    // --- parameter de-normalization ---
    const float lo[13] = {1.f,50.f,0.05f,0.01f,0.001f,0.2f,0.f,0.f,-2.5f,0.5f,0.f,0.f,0.3f};
    const float hi[13] = {6.f,1000.f,0.9f,0.5f,0.2f,1.f,10.f,100.f,2.5f,10.f,0.1f,0.2f,5.f};
    float p[13];
    const float* pg = params + ((size_t)g * 13) * 16 + m;
#pragma unroll
    for (int i = 0; i < 13; ++i) p[i] = lo[i] + pg[(size_t)i * 16] * (hi[i] - lo[i]);

    Par c;
    c.TT      = p[8];
    c.cfmax   = p[9];
    c.cfmaxTT = p[9] * p[8];
    c.cfrXcf  = p[10] * p[9];
    c.cfrTT   = c.cfrXcf * p[8];
    c.CWH     = p[11];
    c.beta    = p[0];
    c.betaC   = -p[0] * fast_log2(p[1]);
    c.FC      = p[1];
    c.betaet  = p[12];
    c.betaetC = -p[12] * fast_log2(p[5] * p[1]);
    c.PERC    = p[6];
    c.omK0    = 1.0f - p[2];
    c.k0uzl   = p[2] * p[7];
    c.omK1    = 1.0f - p[3];
    c.K2      = p[4];

    float SP = 0.001f, MW = 0.001f, SM = 0.001f, SUZ = 0.001f, SLZ = 0.001f;

    float4 xv[16];
    float Aa[16], Eta[16], cEa[16];
    float Ab[16], Etb[16], cEb[16];
    float qbuf[16];
    float infl = 0.0f;

    // prologue: stage chunks 0,1; snow chunk 0 -> 'a'
    ISSUE(0, 0);
    ISSUE(1, 16);
    WAITV(4);                         // chunk 0 staged (4 oldest of 8)
    LOAD_XV(0);
    snow_pass<0, 16>(xv, SP, MW, Aa, Eta, cEa, c);

    // body k: WAITV(1) drains chunk k+1's 4 staging loads (keeps only the
    // newest op, the k-1 q-store, in flight); hoist x; issue chunk k+2;
    // fused steps; tail routing; reduce+store.
#define BODY_W(K, WN, AC_, ETC_, CEC_, AN_, ETN_, CEN_)                        \
    WAITV(WN);                                                                 \
    LOAD_XV(((K) + 1) & 1);                                                    \
    ISSUE((K) & 1, ((K) + 2) * 16);                                            \
    steps_pass<0, 16, true>(xv, AC_, ETC_, CEC_, AN_, ETN_, CEN_, qbuf, infl,  \
                            SM, SUZ, SLZ, SP, MW, c);                          \
    qbuf[15] = route_step(infl, SUZ, SLZ, c);                                  \
    REDUCE_STORE((K) * 16, 16);

    // k=0: only chunk-1's 4 gll outstanding -> full drain
    BODY_W(0, 0, Aa, Eta, cEa, Ab, Etb, cEb);

    // k = 1..44 as 22 parity pairs
    for (int kk = 0; kk < 22; ++kk) {
        const int k0 = 1 + kk * 2;
        BODY_W(k0,     1, Ab, Etb, cEb, Aa, Eta, cEa);
        BODY_W(k0 + 1, 1, Aa, Eta, cEa, Ab, Etb, cEb);
    }
#undef BODY_W

    // epilogue: chunk 45 = steps 720..729, no snow; tail routing(9)
    steps_pass<0, 10, false>(xv, Ab, Etb, cEb, Aa, Eta, cEa, qbuf, infl,
                             SM, SUZ, SLZ, SP, MW, c);
    qbuf[9] = route_step(infl, SUZ, SLZ, c);
    REDUCE_STORE(720, 10);
#undef ISSUE
}

extern "C" void kernel_launch(void* const* d_in, const int* in_sizes, int n_in,
                              void* d_out, int out_size, void* d_ws, size_t ws_size,
                              hipStream_t stream)
{
    const float* x      = (const float*)d_in[0];
    const float* params = (const float*)d_in[1];
    float* out          = (float*)d_out;

    hipLaunchKernelGGL(hbv_kernel, dim3(500), dim3(64), 0, stream, x, params, out);
}

// Round 16
// 80.040 us; speedup vs baseline: 1.0571x; 1.0571x over previous
//
#include <hip/hip_runtime.h>

#define NSTEP  730
#define NGRID  2000
#define PRECSf 1e-5f

#define GLOBAL_AS __attribute__((address_space(1)))
#define LDS_AS    __attribute__((address_space(3)))

__device__ __forceinline__ float fast_exp2(float v) { return __builtin_amdgcn_exp2f(v); }
__device__ __forceinline__ float fast_log2(float v) { return __builtin_amdgcn_logf(v); }
__device__ __forceinline__ float med3(float a, float b, float c) {
    return __builtin_amdgcn_fmed3f(a, b, c);
}

struct Par {
    float TT, cfmax, cfmaxTT, cfrXcf, cfrTT, CWH;
    float beta, betaC, FC, betaet, betaetC;
    float PERC, omK0, k0uzl, omK1, K2;
};

#define MEMFENCE() asm volatile("" ::: "memory")
#define WAITV(N)  asm volatile("s_waitcnt vmcnt(" #N ")" ::: "memory")

// routing sub-step: needs only inflow; advances SUZ/SLZ; returns q
__device__ __forceinline__ float route_step(float infl,
        float& SUZ, float& SLZ, const Par& c)
{
    const float SUZ1  = SUZ + infl;
    const float PERCv = fminf(SUZ1, c.PERC);
    const float SUZ2  = SUZ1 - PERCv;
    const float SUZ3  = fminf(SUZ2, fmaf(c.omK0, SUZ2, c.k0uzl));
    const float SUZ4  = c.omK1 * SUZ3;
    SUZ = SUZ4;
    const float SLZ1 = SLZ + PERCv;
    const float Q2   = c.K2 * SLZ1;
    SLZ = SLZ1 - Q2;
    return (SUZ2 - SUZ4) + Q2;
}

// fused step I: SM chain of chunk k + routing of step I-1 + snow of chunk k+1.
// Independent snow/routing ops are SOURCE-PLACED inside the trans-latency
// gaps of the SM chain (in-order issue: fill must sit between dependents).
template<int I, bool SNOW>
__device__ __forceinline__ void step1(const float4 (&xv)[16],
        const float (&A)[16], const float (&Ets)[16],
        float (&An)[16], float (&Etn)[16],
        float (&qbuf)[16], float& infl,
        float& SM, float& SUZ, float& SLZ,
        float& SP, float& MW, const Par& c)
{
    const float Ac   = A[I];
    const float Et   = Ets[I];
    const float SMpA = SM + Ac;
    const float lg   = fast_log2(SM);                        // T1
    // --- fill 1: snow front half (independent of SM chain) ---
    float rain = 0.0f, SP2v = 0.0f, MW1v = 0.0f, rrawv = 0.0f, Ex = 0.0f;
    if constexpr (SNOW) {
        const float Pt = xv[I].x, Tt = xv[I].y;
        Ex = xv[I].z;
        const float snow = (Tt < c.TT) ? Pt : 0.0f;
        rain = Pt - snow;
        const float mraw = fmaf(c.cfmax, Tt, -c.cfmaxTT);
        rrawv = fmaf(-c.cfrXcf, Tt, c.cfrTT);
        const float SP1 = SP + snow;
        SP2v = med3(SP1 - mraw, 0.0f, SP1);                  // exact: SP1 >= 0
        MW1v = MW + (SP1 - SP2v);
    }
    const float sw = fast_exp2(fmaf(c.beta, lg, c.betaC));   // T2
    // --- fill 2: routing of step I-1 (independent of SM chain) ---
    if constexpr (I >= 1) qbuf[I - 1] = route_step(infl, SUZ, SLZ, c);
    const float SM1 = fmaf(-Ac, sw, SMpA);
    const float lg1 = fast_log2(SM1);                        // T3
    // --- fill 3: snow back half ---
    if constexpr (SNOW) {
        const float MW2 = med3(MW1v - rrawv, 0.0f, MW1v);    // exact: MW1 >= 0
        SP = SP2v + (MW1v - MW2);
        const float tosoil = fmaxf(fmaf(-c.CWH, SP, MW2), 0.0f);
        MW = MW2 - tosoil;
        An[I]  = rain + tosoil;
        Etn[I] = Ex;
    }
    const float SM2 = fminf(SM1, c.FC);
    infl = SMpA - SM2;                                       // for routing at I+1
    const float Ete = Et * fast_exp2(fmaf(c.betaet, lg1, c.betaetC)); // T4
    SM = fmaxf(fmaxf(SM2 - Ete, SM2 - Et), PRECSf);
}

template<int I, int NS, bool SNOW>
__device__ __forceinline__ void steps_pass(const float4 (&xv)[16],
        const float (&A)[16], const float (&Ets)[16],
        float (&An)[16], float (&Etn)[16],
        float (&qbuf)[16], float& infl,
        float& SM, float& SUZ, float& SLZ,
        float& SP, float& MW, const Par& c)
{
    if constexpr (I < NS) {
        step1<I, SNOW>(xv, A, Ets, An, Etn, qbuf, infl, SM, SUZ, SLZ, SP, MW, c);
        steps_pass<I + 1, NS, SNOW>(xv, A, Ets, An, Etn, qbuf, infl,
                                    SM, SUZ, SLZ, SP, MW, c);
    }
}

// prologue-only: snow for chunk 0
template<int I, int NS>
__device__ __forceinline__ void snow_pass(const float4 (&xv)[16],
        float& SP, float& MW, float (&A)[16], float (&Ets)[16], const Par& c)
{
    if constexpr (I < NS) {
        const float Pt = xv[I].x, Tt = xv[I].y, Ex = xv[I].z;
        const float snow = (Tt < c.TT) ? Pt : 0.0f;
        const float rain = Pt - snow;
        const float mraw = fmaf(c.cfmax, Tt, -c.cfmaxTT);
        const float rraw = fmaf(-c.cfrXcf, Tt, c.cfrTT);
        const float SP1  = SP + snow;
        const float SP2  = med3(SP1 - mraw, 0.0f, SP1);
        const float MW1  = MW + (SP1 - SP2);
        const float MW2  = med3(MW1 - rraw, 0.0f, MW1);
        SP = SP2 + (MW1 - MW2);
        const float tosoil = fmaxf(fmaf(-c.CWH, SP, MW2), 0.0f);
        MW = MW2 - tosoil;
        A[I]   = rain + tosoil;
        Ets[I] = Ex;
        snow_pass<I + 1, NS>(xv, SP, MW, A, Ets, c);
    }
}

// hoisted LDS->reg burst for one chunk (fences pin it; scalar pin anchors values)
#define LOAD_XV(B)                                                             \
    _Pragma("unroll")                                                          \
    for (int ii = 0; ii < 16; ++ii)                                            \
        xv[ii] = *reinterpret_cast<const float4*>(&xs[B][ii * 16 + crow * 4]); \
    asm volatile("" :: "v"(xv[0].x),  "v"(xv[1].x),  "v"(xv[2].x),             \
                       "v"(xv[3].x),  "v"(xv[4].x),  "v"(xv[5].x),             \
                       "v"(xv[6].x),  "v"(xv[7].x),  "v"(xv[8].x),             \
                       "v"(xv[9].x),  "v"(xv[10].x), "v"(xv[11].x),            \
                       "v"(xv[12].x), "v"(xv[13].x), "v"(xv[14].x),            \
                       "v"(xv[15].x))

// chunk-end reduce: transpose 16x16 (per cell) through LDS, tree-sum, store.
#define REDUCE_STORE(T0, N) do {                                               \
    float* qrow = &qt[crow * 336 + m * 20];                                    \
    *reinterpret_cast<float4*>(qrow + 0)  = make_float4(qbuf[0], qbuf[1], qbuf[2], qbuf[3]);    \
    *reinterpret_cast<float4*>(qrow + 4)  = make_float4(qbuf[4], qbuf[5], qbuf[6], qbuf[7]);    \
    *reinterpret_cast<float4*>(qrow + 8)  = make_float4(qbuf[8], qbuf[9], qbuf[10], qbuf[11]);  \
    *reinterpret_cast<float4*>(qrow + 12) = make_float4(qbuf[12], qbuf[13], qbuf[14], qbuf[15]);\
    const float* qcol = &qt[crow * 336 + m];                                   \
    float s0 = qcol[0*20]  + qcol[1*20];                                       \
    float s1 = qcol[2*20]  + qcol[3*20];                                       \
    float s2 = qcol[4*20]  + qcol[5*20];                                       \
    float s3 = qcol[6*20]  + qcol[7*20];                                       \
    float s4 = qcol[8*20]  + qcol[9*20];                                       \
    float s5 = qcol[10*20] + qcol[11*20];                                      \
    float s6 = qcol[12*20] + qcol[13*20];                                      \
    float s7 = qcol[14*20] + qcol[15*20];                                      \
    s0 += s1; s2 += s3; s4 += s5; s6 += s7;                                    \
    s0 += s2; s4 += s6; s0 += s4;                                              \
    if (m < (N)) out[(size_t)((T0) + m) * NGRID + g] = s0 * 0.0625f;           \
} while (0)

__global__ __launch_bounds__(64, 1)
void hbv_kernel(const float* __restrict__ x,
                const float* __restrict__ params,
                float* __restrict__ out)
{
    // one wave per block: 4 grid cells x 16 members. No barriers needed.
    __shared__ __align__(16) float xs[2][256];   // staging [buf][i*16 + c*4 + comp]
    __shared__ __align__(16) float qt[4 * 336];  // q transpose scratch

    const int lane = threadIdx.x;        // 0..63
    const int g0   = blockIdx.x * 4;
    const int crow = lane >> 4;          // cell within block
    const int m    = lane & 15;          // ensemble member
    const int g    = g0 + crow;

    // per-lane staging source: instruction j stages LDS flat index j*64+lane
    const float* srcb[4];
    int ioff[4];
#pragma unroll
    for (int j = 0; j < 4; ++j) {
        const int flat = j * 64 + lane;
        const int i    = flat >> 4;
        const int cc   = (flat >> 2) & 3;
        int comp       = flat & 3; if (comp == 3) comp = 0;   // pad slot
        srcb[j] = x + (size_t)(g0 + cc) * 3 + comp;
        ioff[j] = i;
    }

#define ISSUE(B, T0) do {                                                      \
    MEMFENCE();                                                                \
    _Pragma("unroll")                                                          \
    for (int j = 0; j < 4; ++j) {                                              \
        int stp = (T0) + ioff[j]; stp = stp < NSTEP ? stp : NSTEP - 1;         \
        const float* s_ = srcb[j] + (size_t)stp * (NGRID * 3);                 \
        __builtin_amdgcn_global_load_lds((const GLOBAL_AS unsigned*)s_,        \
            (LDS_AS unsigned*)&xs[B][j * 64], 4, 0, 0);                        \
    }                                                                          \
    MEMFENCE();                                                                \
} while (0)

    // --- parameter de-normalization ---
    const float lo[13] = {1.f,50.f,0.05f,0.01f,0.001f,0.2f,0.f,0.f,-2.5f,0.5f,0.f,0.f,0.3f};
    const float hi[13] = {6.f,1000.f,0.9f,0.5f,0.2f,1.f,10.f,100.f,2.5f,10.f,0.1f,0.2f,5.f};
    float p[13];
    const float* pg = params + ((size_t)g * 13) * 16 + m;
#pragma unroll
    for (int i = 0; i < 13; ++i) p[i] = lo[i] + pg[(size_t)i * 16] * (hi[i] - lo[i]);

    Par c;
    c.TT      = p[8];
    c.cfmax   = p[9];
    c.cfmaxTT = p[9] * p[8];
    c.cfrXcf  = p[10] * p[9];
    c.cfrTT   = c.cfrXcf * p[8];
    c.CWH     = p[11];
    c.beta    = p[0];
    c.betaC   = -p[0] * fast_log2(p[1]);
    c.FC      = p[1];
    c.betaet  = p[12];
    c.betaetC = -p[12] * fast_log2(p[5] * p[1]);
    c.PERC    = p[6];
    c.omK0    = 1.0f - p[2];
    c.k0uzl   = p[2] * p[7];
    c.omK1    = 1.0f - p[3];
    c.K2      = p[4];

    float SP = 0.001f, MW = 0.001f, SM = 0.001f, SUZ = 0.001f, SLZ = 0.001f;

    float4 xv[16];
    float Aa[16], Eta[16];
    float Ab[16], Etb[16];
    float qbuf[16];
    float infl = 0.0f;

    // prologue: stage chunks 0,1; snow chunk 0 -> 'a'
    ISSUE(0, 0);
    ISSUE(1, 16);
    WAITV(4);                         // chunk 0 staged
    LOAD_XV(0);
    snow_pass<0, 16>(xv, SP, MW, Aa, Eta, c);

    // body k: wait chunk k+1 staged; hoist x; issue chunk k+2;
    //   fused steps (SM chunk k, routing lagged 1, snow chunk k+1);
    //   tail routing(15); transpose-reduce + store chunk k.
#define BODY_W(K, WN, AC_, ETC_, AN_, ETN_)                                    \
    WAITV(WN);                                                                 \
    LOAD_XV(((K) + 1) & 1);                                                    \
    ISSUE((K) & 1, ((K) + 2) * 16);                                            \
    steps_pass<0, 16, true>(xv, AC_, ETC_, AN_, ETN_, qbuf, infl,              \
                            SM, SUZ, SLZ, SP, MW, c);                          \
    qbuf[15] = route_step(infl, SUZ, SLZ, c);                                  \
    REDUCE_STORE((K) * 16, 16);

    // k=0: only chunk-1's 4 gll outstanding -> full drain
    BODY_W(0, 0, Aa, Eta, Ab, Etb);

    // k = 1..44 as 22 parity pairs (WN=16: keep the 16 newer stores in flight,
    // drain the 4 older gll of chunk k+1)
    for (int kk = 0; kk < 22; ++kk) {
        const int k0 = 1 + kk * 2;
        BODY_W(k0,     16, Ab, Etb, Aa, Eta);
        BODY_W(k0 + 1, 16, Aa, Eta, Ab, Etb);
    }
#undef BODY_W

    // epilogue: chunk 45 = steps 720..729, no snow; tail routing(9)
    steps_pass<0, 10, false>(xv, Ab, Etb, Aa, Eta, qbuf, infl,
                             SM, SUZ, SLZ, SP, MW, c);
    qbuf[9] = route_step(infl, SUZ, SLZ, c);
    REDUCE_STORE(720, 10);
#undef ISSUE
}

extern "C" void kernel_launch(void* const* d_in, const int* in_sizes, int n_in,
                              void* d_out, int out_size, void* d_ws, size_t ws_size,
                              hipStream_t stream)
{
    const float* x      = (const float*)d_in[0];
    const float* params = (const float*)d_in[1];
    float* out          = (float*)d_out;

    hipLaunchKernelGGL(hbv_kernel, dim3(500), dim3(64), 0, stream, x, params, out);
}